// Round 1
// baseline (576.922 us; speedup 1.0000x reference)
//
#include <hip/hip_runtime.h>
#include <cstdint>
#include <cstddef>

#define AS1 __attribute__((address_space(1)))
#define AS3 __attribute__((address_space(3)))

using short8 = __attribute__((ext_vector_type(8))) short;
using f32x4  = __attribute__((ext_vector_type(4))) float;

// ---------- bf16 bit helpers (RNE) ----------
__device__ __forceinline__ float bf2f(unsigned short u) {
    union { unsigned int i; float f; } c; c.i = ((unsigned int)u) << 16; return c.f;
}
__device__ __forceinline__ unsigned short f2bf(float f) {
    union { float f; unsigned int i; } c; c.f = f;
    unsigned int u = c.i;
    unsigned int r = u + 0x7FFFu + ((u >> 16) & 1u);
    return (unsigned short)(r >> 16);
}

// ---------- prep kernels ----------
__global__ void split_x_kernel(const float* __restrict__ x,
                               unsigned short* __restrict__ xhi,
                               unsigned short* __restrict__ xlo) {
    int i = (blockIdx.x * 256 + threadIdx.x) * 4;
    float4 v = *(const float4*)(x + i);
    ushort4 hi, lo;
    hi.x = f2bf(v.x); lo.x = f2bf(v.x - bf2f(hi.x));
    hi.y = f2bf(v.y); lo.y = f2bf(v.y - bf2f(hi.y));
    hi.z = f2bf(v.z); lo.z = f2bf(v.z - bf2f(hi.z));
    hi.w = f2bf(v.w); lo.w = f2bf(v.w - bf2f(hi.w));
    *(ushort4*)(xhi + i) = hi;
    *(ushort4*)(xlo + i) = lo;
}

// Bt_split: (1536 e) x (1536 k). e: [q|k|v]*512. k blocks: [W_hi | W_hi | W_lo]
__global__ void prep_bt_kernel(const float* __restrict__ Wq, const float* __restrict__ Wk,
                               const float* __restrict__ Wv, unsigned short* __restrict__ Bt) {
    int i = blockIdx.x * 256 + threadIdx.x;      // [0, 1536*1536)
    int e = i / 1536, k = i - e * 1536;
    int proj = e >> 9, er = e & 511;
    const float* W = (proj == 0) ? Wq : ((proj == 1) ? Wk : Wv);
    int kb = k >> 9, kr = k & 511;
    float w = W[er * 512 + kr];
    unsigned short hi = f2bf(w);
    Bt[i] = (kb < 2) ? hi : f2bf(w - bf2f(hi));
}

__global__ void prep_wo_kernel(const float* __restrict__ Wo, unsigned short* __restrict__ WoB) {
    int i = blockIdx.x * 256 + threadIdx.x;
    WoB[i] = f2bf(Wo[i]);
}

__global__ void prep_bias_kernel(const float* __restrict__ bq, const float* __restrict__ bk,
                                 const float* __restrict__ bv, float* __restrict__ bias) {
    int i = blockIdx.x * 256 + threadIdx.x;   // 1536
    bias[i] = (i < 512) ? bq[i] : ((i < 1024) ? bk[i - 512] : bv[i - 1024]);
}

__global__ void prep_tw_kernel(float2* __restrict__ tw) {
    int p = blockIdx.x * 256 + threadIdx.x;   // 2048
    double th = -2.0 * 3.14159265358979323846 * (double)p / 4096.0;
    tw[p] = make_float2((float)cos(th), (float)sin(th));
}

// ---------- GEMM: C = A * Bt^T (+bias), m97-style ----------
// MODE 0: QKV. A split (Ahi/Alo, 32768x512 each), Bt 1536x1536, N=1536, K=1536.
//         epilogue: proj 0/1 -> transposed fp32 into qT/kT (B,H,D,L); proj 2 -> bf16 v (B,H,L,D)
// MODE 1: out GEMM. A = out_pre bf16 32768x512, Bt = Wo 512x512, write fp32 d_out + bo.
template <int MODE>
__global__ __launch_bounds__(256, 3) void gemm_bt_kernel(
    const unsigned short* __restrict__ Ahi, const unsigned short* __restrict__ Alo,
    const unsigned short* __restrict__ Bt, const float* __restrict__ bias,
    float* __restrict__ qT, float* __restrict__ kT,
    unsigned short* __restrict__ vout, float* __restrict__ Cout)
{
    constexpr int KT   = (MODE == 0) ? 1536 : 512;
    constexpr int NBLK = (MODE == 0) ? 12 : 4;
    __shared__ short As[128 * 32];
    __shared__ short Bs[128 * 32];
    __shared__ float T[64 * 129];

    const int bid = blockIdx.x;
    const int nb = bid % NBLK;
    const int mb = bid / NBLK;
    const int m0 = mb * 128, n0 = nb * 128;
    const int tid = threadIdx.x;
    const int wave = tid >> 6, lane = tid & 63;
    const int wm = (wave & 1) * 64, wn = (wave >> 1) * 64;
    const int lane15 = lane & 15, quad = lane >> 4;
    const int srow = lane >> 2;          // staging: lane -> row within 16-row chunk
    const int scolB = (lane & 3) * 16;   // staging: byte col (4 lanes * 16B = 64B row)

    f32x4 acc[4][4];
#pragma unroll
    for (int mi = 0; mi < 4; mi++)
#pragma unroll
        for (int ni = 0; ni < 4; ni++)
#pragma unroll
            for (int r = 0; r < 4; r++) acc[mi][ni][r] = 0.f;

    for (int kt = 0; kt < KT / 32; kt++) {
        const int kg = kt * 32;
        const unsigned short* Asrc; int ks;
        if (MODE == 0) { const int blk = kg >> 9; ks = kg & 511; Asrc = (blk == 1) ? Alo : Ahi; }
        else           { ks = kg; Asrc = Ahi; }
        __syncthreads();
#pragma unroll
        for (int i = 0; i < 2; i++) {
            const int rb = wave * 32 + i * 16;   // wave-uniform 16-row chunk
            const char* ga = (const char*)Asrc + ((size_t)(m0 + rb + srow)) * 1024 + ks * 2 + scolB;
            const char* gb = (const char*)Bt   + ((size_t)(n0 + rb + srow)) * (KT * 2) + kg * 2 + scolB;
            __builtin_amdgcn_global_load_lds((const AS1 void*)ga, (AS3 void*)((char*)As + rb * 64), 16, 0, 0);
            __builtin_amdgcn_global_load_lds((const AS1 void*)gb, (AS3 void*)((char*)Bs + rb * 64), 16, 0, 0);
        }
        __syncthreads();
        short8 af[4], bfr[4];
#pragma unroll
        for (int mi = 0; mi < 4; mi++)
            af[mi] = *(const short8*)((const char*)As + (wm + mi * 16 + lane15) * 64 + quad * 16);
#pragma unroll
        for (int ni = 0; ni < 4; ni++)
            bfr[ni] = *(const short8*)((const char*)Bs + (wn + ni * 16 + lane15) * 64 + quad * 16);
#pragma unroll
        for (int mi = 0; mi < 4; mi++)
#pragma unroll
            for (int ni = 0; ni < 4; ni++)
                acc[mi][ni] = __builtin_amdgcn_mfma_f32_16x16x32_bf16(af[mi], bfr[ni], acc[mi][ni], 0, 0, 0);
    }

    if (MODE == 1) {
#pragma unroll
        for (int mi = 0; mi < 4; mi++)
#pragma unroll
            for (int ni = 0; ni < 4; ni++) {
                const int n = n0 + wn + ni * 16 + lane15;
                const float bb = bias[n];
#pragma unroll
                for (int r = 0; r < 4; r++) {
                    const int m = m0 + wm + mi * 16 + quad * 4 + r;
                    Cout[(size_t)m * 512 + n] = acc[mi][ni][r] + bb;
                }
            }
        return;
    }
    const int proj = n0 >> 9;
    if (proj == 2) {   // V -> bf16 (B,H,L,D)
#pragma unroll
        for (int mi = 0; mi < 4; mi++)
#pragma unroll
            for (int ni = 0; ni < 4; ni++) {
                const int n = n0 + wn + ni * 16 + lane15;
                const int er = n - 1024, h = er >> 6, d = er & 63;
                const float bb = bias[n];
#pragma unroll
                for (int r = 0; r < 4; r++) {
                    const int m = m0 + wm + mi * 16 + quad * 4 + r;
                    const int b = m >> 12, l = m & 4095;
                    vout[((size_t)((b * 8 + h) * 4096 + l)) * 64 + d] = f2bf(acc[mi][ni][r] + bb);
                }
            }
        return;
    }
    // Q/K -> fp32 transposed (B,H,D,L) via LDS transpose, two n-halves of 64
    float* dst = (proj == 0) ? qT : kT;
    const int b = m0 >> 12, l0 = m0 & 4095;
    for (int half = 0; half < 2; half++) {
        if ((wave >> 1) == half) {
#pragma unroll
            for (int mi = 0; mi < 4; mi++)
#pragma unroll
                for (int ni = 0; ni < 4; ni++) {
                    const int nloc = ni * 16 + lane15;     // 0..63 within half
                    const float bb = bias[n0 + half * 64 + nloc];
#pragma unroll
                    for (int r = 0; r < 4; r++) {
                        const int mloc = wm + mi * 16 + quad * 4 + r;
                        T[nloc * 129 + mloc] = acc[mi][ni][r] + bb;
                    }
                }
        }
        __syncthreads();
        {
            const int nloc = tid >> 2;          // 0..63
            const int mseg = (tid & 3) * 32;
            const int e = n0 + half * 64 + nloc;
            const int er = e - proj * 512, h = er >> 6, d = er & 63;
            float* o = dst + ((size_t)((b * 8 + h) * 64 + d)) * 4096 + l0 + mseg;
            const float* trow = &T[nloc * 129 + mseg];
#pragma unroll
            for (int j = 0; j < 32; j += 4) {
                *(float4*)(o + j) = make_float4(trow[j], trow[j + 1], trow[j + 2], trow[j + 3]);
            }
        }
        __syncthreads();
    }
}

// ---------- FFT (Stockham radix-2 DIF, natural order, e^{-2pi i} forward) ----------
__device__ __forceinline__ float2 cmul(float2 a, float2 b) {
    return make_float2(a.x * b.x - a.y * b.y, a.x * b.y + a.y * b.x);
}

// per block: one (b,h), 8 consecutive d's. Packed FFT(q + i k), accumulate S=Q*conj(K)
// into registers, write partial spectrum.
__global__ __launch_bounds__(256) void fft_partial_kernel(
    const float* __restrict__ qT, const float* __restrict__ kT,
    const float2* __restrict__ tw, float2* __restrict__ spec)
{
    __shared__ float2 bufA[4096];
    __shared__ float2 bufB[4096];
    const int tid = threadIdx.x;
    const int bh = blockIdx.x >> 3, chunk = blockIdx.x & 7;
    float sx[16], sy[16];
#pragma unroll
    for (int i = 0; i < 16; i++) { sx[i] = 0.f; sy[i] = 0.f; }
    const float* qb = qT + (size_t)bh * 64 * 4096;
    const float* kb = kT + (size_t)bh * 64 * 4096;
    for (int dd = 0; dd < 8; dd++) {
        const int d = chunk * 8 + dd;
#pragma unroll
        for (int i = 0; i < 16; i++) {
            const int t = tid + 256 * i;
            bufA[t] = make_float2(qb[d * 4096 + t], kb[d * 4096 + t]);
        }
        __syncthreads();
        float2* X = bufA; float2* Y = bufB;
        for (int st = 0; st < 12; st++) {
            const int s = 1 << st;
            const int m = 2048 >> st;
#pragma unroll
            for (int i = 0; i < 8; i++) {
                const int u = tid + 256 * i;        // < 2048
                const int p = u >> st;
                const int q = u & (s - 1);
                const float2 a = X[q + s * p];
                const float2 c = X[q + s * (p + m)];
                const float2 w = tw[p << st];
                Y[q + s * 2 * p]       = make_float2(a.x + c.x, a.y + c.y);
                Y[q + s * (2 * p + 1)] = cmul(make_float2(a.x - c.x, a.y - c.y), w);
            }
            __syncthreads();
            float2* t2 = X; X = Y; Y = t2;
        }
        // X == bufA (12 stages). Unpack Q,K; accumulate S = Q*conj(K)
#pragma unroll
        for (int i = 0; i < 16; i++) {
            const int f = tid + 256 * i;
            const float2 Zf = X[f];
            const float2 Zm = X[(4096 - f) & 4095];
            const float Qr  = 0.5f * (Zf.x + Zm.x);
            const float Qi  = 0.5f * (Zf.y - Zm.y);
            const float cKr = 0.5f * (Zf.y + Zm.y);   // conj(K).re
            const float cKi = 0.5f * (Zf.x - Zm.x);   // conj(K).im
            sx[i] += Qr * cKr - Qi * cKi;
            sy[i] += Qr * cKi + Qi * cKr;
        }
        __syncthreads();
    }
    float2* out = spec + (size_t)blockIdx.x * 4096;
#pragma unroll
    for (int i = 0; i < 16; i++) out[tid + 256 * i] = make_float2(sx[i], sy[i]);
}

// per block: one (b,h). Sum 8 partials, corr = Re(FFT(conj(S)))/ (L*D); top-8 + softmax.
__global__ __launch_bounds__(256) void reduce_topk_kernel(
    const float2* __restrict__ spec, const float2* __restrict__ tw,
    int* __restrict__ top_idx, float* __restrict__ top_w)
{
    __shared__ float2 bufA[4096];
    __shared__ float2 bufB[4096];
    const int tid = threadIdx.x;
    const int bh = blockIdx.x;
#pragma unroll
    for (int i = 0; i < 16; i++) {
        const int f = tid + 256 * i;
        float sr = 0.f, si = 0.f;
        for (int c = 0; c < 8; c++) {
            const float2 v = spec[((size_t)(bh * 8 + c)) * 4096 + f];
            sr += v.x; si += v.y;
        }
        bufA[f] = make_float2(sr, -si);   // conj
    }
    __syncthreads();
    float2* X = bufA; float2* Y = bufB;
    for (int st = 0; st < 12; st++) {
        const int s = 1 << st;
        const int m = 2048 >> st;
#pragma unroll
        for (int i = 0; i < 8; i++) {
            const int u = tid + 256 * i;
            const int p = u >> st;
            const int q = u & (s - 1);
            const float2 a = X[q + s * p];
            const float2 c = X[q + s * (p + m)];
            const float2 w = tw[p << st];
            Y[q + s * 2 * p]       = make_float2(a.x + c.x, a.y + c.y);
            Y[q + s * (2 * p + 1)] = cmul(make_float2(a.x - c.x, a.y - c.y), w);
        }
        __syncthreads();
        float2* t2 = X; X = Y; Y = t2;
    }
    // X == bufA: corr(tau) ~ X[tau].x (unscaled). Top-8 with lower-index tie-break.
    float* red_v = (float*)bufB;
    int*   red_i = (int*)((char*)bufB + 4096);
    float vals[8]; int idxs[8];
    for (int k = 0; k < 8; k++) {
        float best = -3.0e38f; int bi = 0x7fffffff;
#pragma unroll
        for (int i = 0; i < 16; i++) {
            const int f = tid + 256 * i;
            const float c = bufA[f].x;
            if (c > best) { best = c; bi = f; }
        }
        red_v[tid] = best; red_i[tid] = bi;
        __syncthreads();
        for (int off = 128; off > 0; off >>= 1) {
            if (tid < off) {
                const float ov = red_v[tid + off]; const int oi = red_i[tid + off];
                if (ov > red_v[tid] || (ov == red_v[tid] && oi < red_i[tid])) {
                    red_v[tid] = ov; red_i[tid] = oi;
                }
            }
            __syncthreads();
        }
        best = red_v[0]; bi = red_i[0];
        vals[k] = best; idxs[k] = bi;
        if (tid == (bi & 255)) bufA[bi].x = -3.4e38f;
        __syncthreads();
    }
    if (tid == 0) {
        const float scale = 1.f / (4096.f * 64.f);
        float e[8], s = 0.f;
        const float mx = vals[0] * scale;
        for (int k = 0; k < 8; k++) { e[k] = __expf(vals[k] * scale - mx); s += e[k]; }
        for (int k = 0; k < 8; k++) {
            top_w[bh * 8 + k] = e[k] / s;
            top_idx[bh * 8 + k] = idxs[k];
        }
    }
}

// ---------- gather: out_pre[b,l,h*64+d] = sum_k w_k * v[b,h,(l+idx_k)%L,d] ----------
__global__ __launch_bounds__(256) void gather_kernel(
    const unsigned short* __restrict__ v, const int* __restrict__ top_idx,
    const float* __restrict__ top_w, unsigned short* __restrict__ out_pre)
{
    const int bid = blockIdx.x;           // 65536
    const int slot = bid & 7;             // XCD swizzle: one (b,h) -> one XCD slot
    const int seq = bid >> 3;
    const int bh_grp = seq >> 10;
    const int lchunk = seq & 1023;
    const int bh = bh_grp * 8 + slot;
    const int b = bh >> 3, h = bh & 7;
    const int tid = threadIdx.x;
    const int l = lchunk * 4 + (tid >> 6);
    const int d = tid & 63;
    int idx[8]; float w[8];
#pragma unroll
    for (int k = 0; k < 8; k++) { idx[k] = top_idx[bh * 8 + k]; w[k] = top_w[bh * 8 + k]; }
    const unsigned short* vb = v + (size_t)bh * 4096 * 64;
    float acc = 0.f;
#pragma unroll
    for (int k = 0; k < 8; k++) {
        const int ls = (l + idx[k]) & 4095;
        acc += w[k] * bf2f(vb[ls * 64 + d]);
    }
    out_pre[((size_t)(b * 4096 + l)) * 512 + h * 64 + d] = f2bf(acc);
}

// ---------- host ----------
extern "C" void kernel_launch(void* const* d_in, const int* in_sizes, int n_in,
                              void* d_out, int out_size, void* d_ws, size_t ws_size,
                              hipStream_t stream) {
    (void)in_sizes; (void)n_in; (void)out_size; (void)ws_size;
    const float* x  = (const float*)d_in[0];
    const float* Wq = (const float*)d_in[1];
    const float* bq = (const float*)d_in[2];
    const float* Wk = (const float*)d_in[3];
    const float* bk = (const float*)d_in[4];
    const float* Wv = (const float*)d_in[5];
    const float* bv = (const float*)d_in[6];
    const float* Wo = (const float*)d_in[7];
    const float* bo = (const float*)d_in[8];
    float* out = (float*)d_out;

    char* ws = (char*)d_ws;
    size_t off = 0;
    auto alloc = [&](size_t bytes) -> void* {
        void* p = ws + off; off += (bytes + 255) & ~(size_t)255; return p;
    };
    unsigned short* x_hi = (unsigned short*)alloc(33554432);   // 32768x512 bf16
    unsigned short* x_lo = (unsigned short*)alloc(33554432);
    float* qT            = (float*)alloc(67108864);            // (B,H,D,L) fp32
    float* kT            = (float*)alloc(67108864);
    unsigned short* vbuf = (unsigned short*)alloc(33554432);   // (B,H,L,D) bf16
    unsigned short* BtS  = (unsigned short*)alloc(4718592);    // 1536x1536 bf16
    unsigned short* WoB  = (unsigned short*)alloc(524288);     // 512x512 bf16
    float* biasQKV       = (float*)alloc(6144);                // 1536 fp32
    float2* tw           = (float2*)alloc(16384);              // 2048 twiddles
    int*   top_idx       = (int*)alloc(2048);
    float* top_w         = (float*)alloc(2048);
    float2* spec         = (float2*)x_lo;                      // alias: x_lo dead after GEMM1
    unsigned short* out_pre = x_hi;                            // alias: x_hi dead after GEMM1

    split_x_kernel<<<16384, 256, 0, stream>>>(x, x_hi, x_lo);
    prep_bt_kernel<<<9216, 256, 0, stream>>>(Wq, Wk, Wv, BtS);
    prep_wo_kernel<<<1024, 256, 0, stream>>>(Wo, WoB);
    prep_bias_kernel<<<6, 256, 0, stream>>>(bq, bk, bv, biasQKV);
    prep_tw_kernel<<<8, 256, 0, stream>>>(tw);

    gemm_bt_kernel<0><<<3072, 256, 0, stream>>>(x_hi, x_lo, BtS, biasQKV, qT, kT, vbuf, nullptr);
    fft_partial_kernel<<<512, 256, 0, stream>>>(qT, kT, tw, spec);
    reduce_topk_kernel<<<64, 256, 0, stream>>>(spec, tw, top_idx, top_w);
    gather_kernel<<<65536, 256, 0, stream>>>(vbuf, top_idx, top_w, out_pre);
    gemm_bt_kernel<1><<<1024, 256, 0, stream>>>(out_pre, nullptr, WoB, bo, nullptr, nullptr, nullptr, out);
}

// Round 2
// 522.164 us; speedup vs baseline: 1.1049x; 1.1049x over previous
//
#include <hip/hip_runtime.h>
#include <cstdint>
#include <cstddef>

#define AS1 __attribute__((address_space(1)))
#define AS3 __attribute__((address_space(3)))

using short8 = __attribute__((ext_vector_type(8))) short;
using f32x4  = __attribute__((ext_vector_type(4))) float;

// ---------- bf16 bit helpers (RNE) ----------
__device__ __forceinline__ float bf2f(unsigned int u16) {
    union { unsigned int i; float f; } c; c.i = u16 << 16; return c.f;
}
__device__ __forceinline__ unsigned short f2bf(float f) {
    union { float f; unsigned int i; } c; c.f = f;
    unsigned int u = c.i;
    unsigned int r = u + 0x7FFFu + ((u >> 16) & 1u);
    return (unsigned short)(r >> 16);
}

// ---------- fused prep kernel ----------
// blocks [0,16384): split x -> x_hi/x_lo
// [16384,25600): Bt 1536x1536 (cols 0..511 W_hi, 512..1023 W_hi, 1024..1535 W_lo)
// [25600,26624): Wo -> bf16
// [26624,26632): twiddles (2048)
// [26632,26638): bias concat (1536)
__global__ void prep_all_kernel(const float* __restrict__ x,
                                const float* __restrict__ Wq, const float* __restrict__ Wk,
                                const float* __restrict__ Wv, const float* __restrict__ Wo,
                                const float* __restrict__ bq, const float* __restrict__ bk,
                                const float* __restrict__ bv,
                                unsigned short* __restrict__ xhi, unsigned short* __restrict__ xlo,
                                unsigned short* __restrict__ Bt, unsigned short* __restrict__ WoB,
                                float2* __restrict__ tw, float* __restrict__ bias) {
    const int bid = blockIdx.x;
    const int tid = threadIdx.x;
    if (bid < 16384) {
        int i = (bid * 256 + tid) * 4;
        float4 v = *(const float4*)(x + i);
        ushort4 hi, lo;
        hi.x = f2bf(v.x); lo.x = f2bf(v.x - bf2f(hi.x));
        hi.y = f2bf(v.y); lo.y = f2bf(v.y - bf2f(hi.y));
        hi.z = f2bf(v.z); lo.z = f2bf(v.z - bf2f(hi.z));
        hi.w = f2bf(v.w); lo.w = f2bf(v.w - bf2f(hi.w));
        *(ushort4*)(xhi + i) = hi;
        *(ushort4*)(xlo + i) = lo;
    } else if (bid < 25600) {
        int i = (bid - 16384) * 256 + tid;      // [0, 1536*1536)
        int e = i / 1536, k = i - e * 1536;
        int proj = e >> 9, er = e & 511;
        const float* W = (proj == 0) ? Wq : ((proj == 1) ? Wk : Wv);
        int kb = k >> 9, kr = k & 511;
        float w = W[er * 512 + kr];
        unsigned short hi = f2bf(w);
        Bt[i] = (kb < 2) ? hi : f2bf(w - bf2f(hi));
    } else if (bid < 26624) {
        int i = (bid - 25600) * 256 + tid;
        WoB[i] = f2bf(Wo[i]);
    } else if (bid < 26632) {
        int p = (bid - 26624) * 256 + tid;      // 2048
        double th = -2.0 * 3.14159265358979323846 * (double)p / 4096.0;
        tw[p] = make_float2((float)cos(th), (float)sin(th));
    } else {
        int i = (bid - 26632) * 256 + tid;      // 1536
        bias[i] = (i < 512) ? bq[i] : ((i < 1024) ? bk[i - 512] : bv[i - 1024]);
    }
}

// ---------- GEMM: C = A * Bt^T (+bias), m97-style ----------
// MODE 0: QKV. A split (Ahi/Alo), Bt 1536x1536, N=1536.
//   proj 0/1 (q,k): K=1536 split path; epilogue float4 stores transposed fp32 (B,H,D,L)
//   proj 2 (v):     K=512 plain bf16; epilogue bf16 (B,H,L,D)
// MODE 1: out GEMM. A = out_pre bf16 32768x512, Bt = Wo, fp32 d_out + bo.
template <int MODE>
__global__ __launch_bounds__(256, 4) void gemm_bt_kernel(
    const unsigned short* __restrict__ Ahi, const unsigned short* __restrict__ Alo,
    const unsigned short* __restrict__ Bt, const float* __restrict__ bias,
    float* __restrict__ qT, float* __restrict__ kT,
    unsigned short* __restrict__ vout, float* __restrict__ Cout)
{
    constexpr int KT   = (MODE == 0) ? 1536 : 512;
    constexpr int NBLK = (MODE == 0) ? 12 : 4;
    __shared__ short As[128 * 32];
    __shared__ short Bs[128 * 32];

    const int bid = blockIdx.x;
    const int nb = bid % NBLK;
    const int mb = bid / NBLK;
    const int m0 = mb * 128, n0 = nb * 128;
    const int tid = threadIdx.x;
    const int wave = tid >> 6, lane = tid & 63;
    const int wm = (wave & 1) * 64, wn = (wave >> 1) * 64;
    const int lane15 = lane & 15, quad = lane >> 4;
    const int srow = lane >> 2;          // staging: lane -> row within 16-row chunk
    const int scolB = (lane & 3) * 16;   // staging: byte col

    const int kend = (MODE == 0) ? ((n0 >= 1024) ? 16 : 48) : 16;

    f32x4 acc[4][4];
#pragma unroll
    for (int mi = 0; mi < 4; mi++)
#pragma unroll
        for (int ni = 0; ni < 4; ni++)
#pragma unroll
            for (int r = 0; r < 4; r++) acc[mi][ni][r] = 0.f;

    for (int kt = 0; kt < kend; kt++) {
        const int kg = kt * 32;
        const unsigned short* Asrc; int ks;
        if (MODE == 0) { const int blk = kg >> 9; ks = kg & 511; Asrc = (blk == 1) ? Alo : Ahi; }
        else           { ks = kg; Asrc = Ahi; }
        __syncthreads();
#pragma unroll
        for (int i = 0; i < 2; i++) {
            const int rb = wave * 32 + i * 16;   // wave-uniform 16-row chunk
            const char* ga = (const char*)Asrc + ((size_t)(m0 + rb + srow)) * 1024 + ks * 2 + scolB;
            const char* gb = (const char*)Bt   + ((size_t)(n0 + rb + srow)) * (KT * 2) + kg * 2 + scolB;
            __builtin_amdgcn_global_load_lds((const AS1 void*)ga, (AS3 void*)((char*)As + rb * 64), 16, 0, 0);
            __builtin_amdgcn_global_load_lds((const AS1 void*)gb, (AS3 void*)((char*)Bs + rb * 64), 16, 0, 0);
        }
        __syncthreads();
        short8 af[4], bfr[4];
#pragma unroll
        for (int mi = 0; mi < 4; mi++)
            af[mi] = *(const short8*)((const char*)As + (wm + mi * 16 + lane15) * 64 + quad * 16);
#pragma unroll
        for (int ni = 0; ni < 4; ni++)
            bfr[ni] = *(const short8*)((const char*)Bs + (wn + ni * 16 + lane15) * 64 + quad * 16);
#pragma unroll
        for (int mi = 0; mi < 4; mi++)
#pragma unroll
            for (int ni = 0; ni < 4; ni++)
                acc[mi][ni] = __builtin_amdgcn_mfma_f32_16x16x32_bf16(af[mi], bfr[ni], acc[mi][ni], 0, 0, 0);
    }

    if (MODE == 1) {
#pragma unroll
        for (int mi = 0; mi < 4; mi++)
#pragma unroll
            for (int ni = 0; ni < 4; ni++) {
                const int n = n0 + wn + ni * 16 + lane15;
                const float bb = bias[n];
#pragma unroll
                for (int r = 0; r < 4; r++) {
                    const int m = m0 + wm + mi * 16 + quad * 4 + r;
                    Cout[(size_t)m * 512 + n] = acc[mi][ni][r] + bb;
                }
            }
        return;
    }
    const int proj = n0 >> 9;
    if (proj == 2) {   // V -> bf16 (B,H,L,D)
#pragma unroll
        for (int mi = 0; mi < 4; mi++)
#pragma unroll
            for (int ni = 0; ni < 4; ni++) {
                const int n = n0 + wn + ni * 16 + lane15;
                const int er = n - 1024, h = er >> 6, d = er & 63;
                const float bb = bias[n];
#pragma unroll
                for (int r = 0; r < 4; r++) {
                    const int m = m0 + wm + mi * 16 + quad * 4 + r;
                    const int b = m >> 12, l = m & 4095;
                    vout[((size_t)((b * 8 + h) * 4096 + l)) * 64 + d] = f2bf(acc[mi][ni][r] + bb);
                }
            }
        return;
    }
    // Q/K: direct transposed float4 stores. Lane holds 4 consecutive l (quad*4+r).
    float* dst = (proj == 0) ? qT : kT;
    const int b = m0 >> 12;
    const int lbase = (m0 & 4095) + wm + quad * 4;
#pragma unroll
    for (int mi = 0; mi < 4; mi++)
#pragma unroll
        for (int ni = 0; ni < 4; ni++) {
            const int e = n0 + wn + ni * 16 + lane15;
            const int er = e & 511, h = er >> 6, d = er & 63;
            const float bb = bias[e];
            float4 o4 = make_float4(acc[mi][ni][0] + bb, acc[mi][ni][1] + bb,
                                    acc[mi][ni][2] + bb, acc[mi][ni][3] + bb);
            *(float4*)(dst + ((size_t)((b * 8 + h) * 64 + d)) * 4096 + lbase + mi * 16) = o4;
        }
}

// ---------- FFT: 4096-pt, radix-4 Stockham (fused from verified radix-2), swizzled LDS ----------
__device__ __forceinline__ float2 cmul(float2 a, float2 b) {
    return make_float2(a.x * b.x - a.y * b.y, a.x * b.y + a.y * b.x);
}
__device__ __forceinline__ int swz(int i) { return i ^ ((i >> 4) & 15); }

// result lands in bufA (natural order, swizzled addressing). Syncs internally
// (including entry sync covering the caller's fill and exit sync covering last writes).
__device__ __forceinline__ void fft4096(float2* bufA, float2* bufB,
                                        const float2* __restrict__ tw, int tid) {
    float2* X = bufA; float2* Y = bufB;
#pragma unroll
    for (int st2 = 0; st2 < 6; st2++) {
        const int st = 2 * st2;
        const int s = 1 << st;
        __syncthreads();
#pragma unroll
        for (int i = 0; i < 4; i++) {
            const int u = tid + 256 * i;
            const int q = u & (s - 1);
            const int p2 = u >> st;
            const float2 x0 = X[swz(u)];
            const float2 x1 = X[swz(u + 1024)];
            const float2 x2 = X[swz(u + 2048)];
            const float2 x3 = X[swz(u + 3072)];
            const float2 Ea = make_float2(x0.x + x2.x, x0.y + x2.y);
            const float2 Oa = make_float2(x0.x - x2.x, x0.y - x2.y);
            const float2 Eb = make_float2(x1.x + x3.x, x1.y + x3.y);
            const float2 Ob = make_float2(x1.x - x3.x, x1.y - x3.y);
            const float2 w1 = tw[p2 << st];
            const float2 w2 = tw[p2 << (st + 1)];
            const float2 w3 = cmul(w1, w2);
            const int o = q + (p2 << (st + 2));
            Y[swz(o)]         = make_float2(Ea.x + Eb.x, Ea.y + Eb.y);
            Y[swz(o + s)]     = cmul(make_float2(Oa.x + Ob.y, Oa.y - Ob.x), w1);  // (Oa - i*Ob)*w1
            Y[swz(o + 2 * s)] = cmul(make_float2(Ea.x - Eb.x, Ea.y - Eb.y), w2);
            Y[swz(o + 3 * s)] = cmul(make_float2(Oa.x - Ob.y, Oa.y + Ob.x), w3);  // (Oa + i*Ob)*w3
        }
        float2* tmp = X; X = Y; Y = tmp;
    }
    __syncthreads();
}

// per block: one (b,h), 8 d's. Packed FFT(q + i k), accumulate S=Q*conj(K), write partial.
__global__ __launch_bounds__(256) void fft_partial_kernel(
    const float* __restrict__ qT, const float* __restrict__ kT,
    const float2* __restrict__ tw, float2* __restrict__ spec)
{
    __shared__ float2 bufA[4096];
    __shared__ float2 bufB[4096];
    const int tid = threadIdx.x;
    const int bh = blockIdx.x >> 3, chunk = blockIdx.x & 7;
    float sx[16], sy[16];
#pragma unroll
    for (int i = 0; i < 16; i++) { sx[i] = 0.f; sy[i] = 0.f; }
    const float* qb = qT + (size_t)bh * 64 * 4096;
    const float* kb = kT + (size_t)bh * 64 * 4096;
    for (int dd = 0; dd < 8; dd++) {
        const int d = chunk * 8 + dd;
#pragma unroll
        for (int i = 0; i < 4; i++) {
            const int t0 = 1024 * i + tid * 4;
            const float4 fq = *(const float4*)(qb + d * 4096 + t0);
            const float4 fk = *(const float4*)(kb + d * 4096 + t0);
            bufA[swz(t0 + 0)] = make_float2(fq.x, fk.x);
            bufA[swz(t0 + 1)] = make_float2(fq.y, fk.y);
            bufA[swz(t0 + 2)] = make_float2(fq.z, fk.z);
            bufA[swz(t0 + 3)] = make_float2(fq.w, fk.w);
        }
        fft4096(bufA, bufB, tw, tid);
        // unpack packed transforms; accumulate S = Q * conj(K)
#pragma unroll
        for (int i = 0; i < 16; i++) {
            const int f = tid + 256 * i;
            const float2 Zf = bufA[swz(f)];
            const float2 Zm = bufA[swz((4096 - f) & 4095)];
            const float Qr  = 0.5f * (Zf.x + Zm.x);
            const float Qi  = 0.5f * (Zf.y - Zm.y);
            const float cKr = 0.5f * (Zf.y + Zm.y);
            const float cKi = 0.5f * (Zf.x - Zm.x);
            sx[i] += Qr * cKr - Qi * cKi;
            sy[i] += Qr * cKi + Qi * cKr;
        }
        __syncthreads();
    }
    float2* out = spec + (size_t)blockIdx.x * 4096;
#pragma unroll
    for (int i = 0; i < 16; i++) out[tid + 256 * i] = make_float2(sx[i], sy[i]);
}

// per block: one (b,h). Sum 8 partials, corr = Re(FFT(conj(S))); top-8 + softmax.
__global__ __launch_bounds__(256) void reduce_topk_kernel(
    const float2* __restrict__ spec, const float2* __restrict__ tw,
    int* __restrict__ top_idx, float* __restrict__ top_w)
{
    __shared__ float2 bufA[4096];
    __shared__ float2 bufB[4096];
    const int tid = threadIdx.x;
    const int bh = blockIdx.x;
#pragma unroll
    for (int i = 0; i < 16; i++) {
        const int f = tid + 256 * i;
        float sr = 0.f, si = 0.f;
        for (int c = 0; c < 8; c++) {
            const float2 v = spec[((size_t)(bh * 8 + c)) * 4096 + f];
            sr += v.x; si += v.y;
        }
        bufA[swz(f)] = make_float2(sr, -si);   // conj
    }
    fft4096(bufA, bufB, tw, tid);
    // bufA[tau].x ~ corr(tau) (unscaled). Top-8, lower-index tie-break.
    float* wv = (float*)bufB;        // bufB free after FFT
    int*   wi = (int*)bufB + 8;
    float vals[8]; int idxs[8];
    for (int k = 0; k < 8; k++) {
        float best = -3.0e38f; int bi = 0;
#pragma unroll
        for (int i = 0; i < 16; i++) {
            const int f = tid + 256 * i;
            const float c = bufA[swz(f)].x;
            if (c > best) { best = c; bi = f; }
        }
#pragma unroll
        for (int off = 32; off > 0; off >>= 1) {
            const float ov = __shfl_down(best, off);
            const int oi = __shfl_down(bi, off);
            if (ov > best || (ov == best && oi < bi)) { best = ov; bi = oi; }
        }
        if ((tid & 63) == 0) { wv[tid >> 6] = best; wi[tid >> 6] = bi; }
        __syncthreads();
        if (tid == 0) {
            best = wv[0]; bi = wi[0];
            for (int w = 1; w < 4; w++) {
                if (wv[w] > best || (wv[w] == best && wi[w] < bi)) { best = wv[w]; bi = wi[w]; }
            }
            vals[k] = best; idxs[k] = bi;
            bufA[swz(bi)].x = -3.4e38f;
        }
        __syncthreads();
    }
    if (tid == 0) {
        const float scale = 1.f / (4096.f * 64.f);
        float e[8], s = 0.f;
        const float mx = vals[0] * scale;
        for (int k = 0; k < 8; k++) { e[k] = __expf(vals[k] * scale - mx); s += e[k]; }
        for (int k = 0; k < 8; k++) {
            top_w[bh * 8 + k] = e[k] / s;
            top_idx[bh * 8 + k] = idxs[k];
        }
    }
}

// ---------- gather: out_pre[b,l,h*64+d] = sum_k w_k * v[b,h,(l+idx_k)%L,d] ----------
__global__ __launch_bounds__(256) void gather_kernel(
    const unsigned int* __restrict__ v32, const int* __restrict__ top_idx,
    const float* __restrict__ top_w, unsigned int* __restrict__ out32)
{
    const int seq = blockIdx.x;           // 32768
    const int bh = seq >> 9;
    const int lgrp = seq & 511;
    const int b = bh >> 3, h = bh & 7;
    const int tid = threadIdx.x;
    const int l = lgrp * 8 + (tid >> 5);
    const int d2 = tid & 31;              // uint index (2 bf16 per uint)
    int idx[8]; float w[8];
#pragma unroll
    for (int k = 0; k < 8; k++) { idx[k] = top_idx[bh * 8 + k]; w[k] = top_w[bh * 8 + k]; }
    const unsigned int* vb = v32 + (size_t)bh * 4096 * 32;
    float a0 = 0.f, a1 = 0.f;
#pragma unroll
    for (int k = 0; k < 8; k++) {
        const int ls = (l + idx[k]) & 4095;
        const unsigned int pv = vb[ls * 32 + d2];
        a0 += w[k] * bf2f(pv & 0xffffu);
        a1 += w[k] * bf2f(pv >> 16);
    }
    out32[((size_t)(b * 4096 + l)) * 256 + h * 32 + d2] =
        (unsigned int)f2bf(a0) | ((unsigned int)f2bf(a1) << 16);
}

// ---------- host ----------
extern "C" void kernel_launch(void* const* d_in, const int* in_sizes, int n_in,
                              void* d_out, int out_size, void* d_ws, size_t ws_size,
                              hipStream_t stream) {
    (void)in_sizes; (void)n_in; (void)out_size; (void)ws_size;
    const float* x  = (const float*)d_in[0];
    const float* Wq = (const float*)d_in[1];
    const float* bq = (const float*)d_in[2];
    const float* Wk = (const float*)d_in[3];
    const float* bk = (const float*)d_in[4];
    const float* Wv = (const float*)d_in[5];
    const float* bv = (const float*)d_in[6];
    const float* Wo = (const float*)d_in[7];
    const float* bo = (const float*)d_in[8];
    float* out = (float*)d_out;

    char* ws = (char*)d_ws;
    size_t off = 0;
    auto alloc = [&](size_t bytes) -> void* {
        void* p = ws + off; off += (bytes + 255) & ~(size_t)255; return p;
    };
    unsigned short* x_hi = (unsigned short*)alloc(33554432);   // 32768x512 bf16
    unsigned short* x_lo = (unsigned short*)alloc(33554432);
    float* qT            = (float*)alloc(67108864);            // (B,H,D,L) fp32
    float* kT            = (float*)alloc(67108864);
    unsigned short* vbuf = (unsigned short*)alloc(33554432);   // (B,H,L,D) bf16
    unsigned short* BtS  = (unsigned short*)alloc(4718592);    // 1536x1536 bf16
    unsigned short* WoB  = (unsigned short*)alloc(524288);     // 512x512 bf16
    float* biasQKV       = (float*)alloc(6144);                // 1536 fp32
    float2* tw           = (float2*)alloc(16384);              // 2048 twiddles
    int*   top_idx       = (int*)alloc(2048);
    float* top_w         = (float*)alloc(2048);
    float2* spec         = (float2*)x_lo;                      // alias: x_lo dead after GEMM1
    unsigned short* out_pre = x_hi;                            // alias: x_hi dead after GEMM1

    prep_all_kernel<<<26638, 256, 0, stream>>>(x, Wq, Wk, Wv, Wo, bq, bk, bv,
                                               x_hi, x_lo, BtS, WoB, tw, biasQKV);
    gemm_bt_kernel<0><<<3072, 256, 0, stream>>>(x_hi, x_lo, BtS, biasQKV, qT, kT, vbuf, nullptr);
    fft_partial_kernel<<<512, 256, 0, stream>>>(qT, kT, tw, spec);
    reduce_topk_kernel<<<64, 256, 0, stream>>>(spec, tw, top_idx, top_w);
    gather_kernel<<<32768, 256, 0, stream>>>((const unsigned int*)vbuf, top_idx, top_w,
                                             (unsigned int*)out_pre);
    gemm_bt_kernel<1><<<1024, 256, 0, stream>>>(out_pre, nullptr, WoB, bo, nullptr, nullptr, nullptr, out);
}

// Round 3
// 378.882 us; speedup vs baseline: 1.5227x; 1.3782x over previous
//
#include <hip/hip_runtime.h>
#include <cstdint>
#include <cstddef>

#define AS1 __attribute__((address_space(1)))
#define AS3 __attribute__((address_space(3)))

using half8  = __attribute__((ext_vector_type(8))) _Float16;
using half4v = __attribute__((ext_vector_type(4))) _Float16;
using half2v = __attribute__((ext_vector_type(2))) _Float16;
using f32x4  = __attribute__((ext_vector_type(4))) float;

// ---------- fused prep kernel ----------
// [0,16384):        x -> fp16 (16.8M elems, 4/thread)
// [16384,19456):    Bt 1536x512 fp16 (rows: q|k|v projection weights)
// [19456,20480):    Wo -> fp16 512x512
// [20480,20488):    twiddles (2048)
// [20488,20494):    bias concat (1536)
__global__ void prep_all_kernel(const float* __restrict__ x,
                                const float* __restrict__ Wq, const float* __restrict__ Wk,
                                const float* __restrict__ Wv, const float* __restrict__ Wo,
                                const float* __restrict__ bq, const float* __restrict__ bk,
                                const float* __restrict__ bv,
                                _Float16* __restrict__ xh, _Float16* __restrict__ Bt,
                                _Float16* __restrict__ WoH,
                                float2* __restrict__ tw, float* __restrict__ bias) {
    const int bid = blockIdx.x;
    const int tid = threadIdx.x;
    if (bid < 16384) {
        int i = (bid * 256 + tid) * 4;
        float4 v = *(const float4*)(x + i);
        half4v h;
        h[0] = (_Float16)v.x; h[1] = (_Float16)v.y;
        h[2] = (_Float16)v.z; h[3] = (_Float16)v.w;
        *(half4v*)(xh + i) = h;
    } else if (bid < 19456) {
        int i = (bid - 16384) * 256 + tid;      // [0, 1536*512)
        int e = i >> 9, k = i & 511;
        int proj = e >> 9, er = e & 511;
        const float* W = (proj == 0) ? Wq : ((proj == 1) ? Wk : Wv);
        Bt[i] = (_Float16)W[er * 512 + k];
    } else if (bid < 20480) {
        int i = (bid - 19456) * 256 + tid;
        WoH[i] = (_Float16)Wo[i];
    } else if (bid < 20488) {
        int p = (bid - 20480) * 256 + tid;      // 2048
        double th = -2.0 * 3.14159265358979323846 * (double)p / 4096.0;
        tw[p] = make_float2((float)cos(th), (float)sin(th));
    } else {
        int i = (bid - 20488) * 256 + tid;      // 1536
        bias[i] = (i < 512) ? bq[i] : ((i < 1024) ? bk[i - 512] : bv[i - 1024]);
    }
}

// ---------- GEMM: C = A * Bt^T (+bias), fp16, K=512, m97-style ----------
// MODE 0: A = x fp16 (32768x512), Bt 1536x512, N=1536.
//   proj 0/1 (q,k): epilogue packed-fp16 transposed stores -> qT/kT (B,H,D,L)
//   proj 2 (v):     epilogue fp16 (B,H,L,D)
// MODE 1: A = out_pre fp16 (32768x512), Bt = WoH 512x512, fp32 d_out + bo.
template <int MODE>
__global__ __launch_bounds__(256, 4) void gemm_f16_kernel(
    const _Float16* __restrict__ A, const _Float16* __restrict__ Bt,
    const float* __restrict__ bias,
    _Float16* __restrict__ qT, _Float16* __restrict__ kT,
    _Float16* __restrict__ vout, float* __restrict__ Cout)
{
    constexpr int NBLK  = (MODE == 0) ? 12 : 4;
    constexpr int PERXCD = (MODE == 0) ? 384 : 128;   // blocks per XCD slot
    __shared__ _Float16 As[128 * 32];
    __shared__ _Float16 Bs[128 * 32];

    // XCD-aware swizzle: same-mb blocks (sharing the A-tile) colocate on one XCD's L2.
    const int gi = (blockIdx.x & 7) * PERXCD + (blockIdx.x >> 3);
    const int mb = gi / NBLK;
    const int nb = gi - mb * NBLK;
    const int m0 = mb * 128, n0 = nb * 128;
    const int tid = threadIdx.x;
    const int wave = tid >> 6, lane = tid & 63;
    const int wm = (wave & 1) * 64, wn = (wave >> 1) * 64;
    const int lane15 = lane & 15, quad = lane >> 4;
    const int srow = lane >> 2;          // staging: lane -> row within 16-row chunk
    const int scolB = (lane & 3) * 16;   // staging: byte col

    f32x4 acc[4][4];
#pragma unroll
    for (int mi = 0; mi < 4; mi++)
#pragma unroll
        for (int ni = 0; ni < 4; ni++)
#pragma unroll
            for (int r = 0; r < 4; r++) acc[mi][ni][r] = 0.f;

    for (int kt = 0; kt < 16; kt++) {
        const int kg = kt * 32;
        __syncthreads();
#pragma unroll
        for (int i = 0; i < 2; i++) {
            const int rb = wave * 32 + i * 16;   // wave-uniform 16-row chunk
            const char* ga = (const char*)A  + ((size_t)(m0 + rb + srow)) * 1024 + kg * 2 + scolB;
            const char* gb = (const char*)Bt + ((size_t)(n0 + rb + srow)) * 1024 + kg * 2 + scolB;
            __builtin_amdgcn_global_load_lds((const AS1 void*)ga, (AS3 void*)((char*)As + rb * 64), 16, 0, 0);
            __builtin_amdgcn_global_load_lds((const AS1 void*)gb, (AS3 void*)((char*)Bs + rb * 64), 16, 0, 0);
        }
        __syncthreads();
        half8 af[4], bfr[4];
#pragma unroll
        for (int mi = 0; mi < 4; mi++)
            af[mi] = *(const half8*)((const char*)As + (wm + mi * 16 + lane15) * 64 + quad * 16);
#pragma unroll
        for (int ni = 0; ni < 4; ni++)
            bfr[ni] = *(const half8*)((const char*)Bs + (wn + ni * 16 + lane15) * 64 + quad * 16);
#pragma unroll
        for (int mi = 0; mi < 4; mi++)
#pragma unroll
            for (int ni = 0; ni < 4; ni++)
                acc[mi][ni] = __builtin_amdgcn_mfma_f32_16x16x32_f16(af[mi], bfr[ni], acc[mi][ni], 0, 0, 0);
    }

    if (MODE == 1) {
#pragma unroll
        for (int mi = 0; mi < 4; mi++)
#pragma unroll
            for (int ni = 0; ni < 4; ni++) {
                const int n = n0 + wn + ni * 16 + lane15;
                const float bb = bias[n];
#pragma unroll
                for (int r = 0; r < 4; r++) {
                    const int m = m0 + wm + mi * 16 + quad * 4 + r;
                    Cout[(size_t)m * 512 + n] = acc[mi][ni][r] + bb;
                }
            }
        return;
    }
    const int proj = n0 >> 9;
    if (proj == 2) {   // V -> fp16 (B,H,L,D)
#pragma unroll
        for (int mi = 0; mi < 4; mi++)
#pragma unroll
            for (int ni = 0; ni < 4; ni++) {
                const int n = n0 + wn + ni * 16 + lane15;
                const int er = n - 1024, h = er >> 6, d = er & 63;
                const float bb = bias[n];
#pragma unroll
                for (int r = 0; r < 4; r++) {
                    const int m = m0 + wm + mi * 16 + quad * 4 + r;
                    const int b = m >> 12, l = m & 4095;
                    vout[((size_t)((b * 8 + h) * 4096 + l)) * 64 + d] = (_Float16)(acc[mi][ni][r] + bb);
                }
            }
        return;
    }
    // Q/K: packed-fp16 transposed stores. Lane holds 4 consecutive l (quad*4+r).
    _Float16* dst = (proj == 0) ? qT : kT;
    const int b = m0 >> 12;
    const int lbase = (m0 & 4095) + wm + quad * 4;
#pragma unroll
    for (int mi = 0; mi < 4; mi++)
#pragma unroll
        for (int ni = 0; ni < 4; ni++) {
            const int e = n0 + wn + ni * 16 + lane15;
            const int er = e & 511, h = er >> 6, d = er & 63;
            const float bb = bias[e];
            half4v o;
            o[0] = (_Float16)(acc[mi][ni][0] + bb);
            o[1] = (_Float16)(acc[mi][ni][1] + bb);
            o[2] = (_Float16)(acc[mi][ni][2] + bb);
            o[3] = (_Float16)(acc[mi][ni][3] + bb);
            *(half4v*)(dst + ((size_t)((b * 8 + h) * 64 + d)) * 4096 + lbase + mi * 16) = o;
        }
}

// ---------- FFT: 4096-pt, radix-4 Stockham, swizzled LDS ----------
__device__ __forceinline__ float2 cmul(float2 a, float2 b) {
    return make_float2(a.x * b.x - a.y * b.y, a.x * b.y + a.y * b.x);
}
__device__ __forceinline__ int swz(int i) { return i ^ ((i >> 4) & 15); }

// result lands in bufA (natural order, swizzled addressing). Syncs internally.
__device__ __forceinline__ void fft4096(float2* bufA, float2* bufB,
                                        const float2* __restrict__ tw, int tid) {
    float2* X = bufA; float2* Y = bufB;
#pragma unroll
    for (int st2 = 0; st2 < 6; st2++) {
        const int st = 2 * st2;
        const int s = 1 << st;
        __syncthreads();
#pragma unroll
        for (int i = 0; i < 4; i++) {
            const int u = tid + 256 * i;
            const int q = u & (s - 1);
            const int p2 = u >> st;
            const float2 x0 = X[swz(u)];
            const float2 x1 = X[swz(u + 1024)];
            const float2 x2 = X[swz(u + 2048)];
            const float2 x3 = X[swz(u + 3072)];
            const float2 Ea = make_float2(x0.x + x2.x, x0.y + x2.y);
            const float2 Oa = make_float2(x0.x - x2.x, x0.y - x2.y);
            const float2 Eb = make_float2(x1.x + x3.x, x1.y + x3.y);
            const float2 Ob = make_float2(x1.x - x3.x, x1.y - x3.y);
            const float2 w1 = tw[p2 << st];
            const float2 w2 = tw[p2 << (st + 1)];
            const float2 w3 = cmul(w1, w2);
            const int o = q + (p2 << (st + 2));
            Y[swz(o)]         = make_float2(Ea.x + Eb.x, Ea.y + Eb.y);
            Y[swz(o + s)]     = cmul(make_float2(Oa.x + Ob.y, Oa.y - Ob.x), w1);  // (Oa - i*Ob)*w1
            Y[swz(o + 2 * s)] = cmul(make_float2(Ea.x - Eb.x, Ea.y - Eb.y), w2);
            Y[swz(o + 3 * s)] = cmul(make_float2(Oa.x - Ob.y, Oa.y + Ob.x), w3);  // (Oa + i*Ob)*w3
        }
        float2* tmp = X; X = Y; Y = tmp;
    }
    __syncthreads();
}

// per block: one (b,h), 8 d's. Packed FFT(q + i k), accumulate S=Q*conj(K), write partial.
__global__ __launch_bounds__(256) void fft_partial_kernel(
    const _Float16* __restrict__ qT, const _Float16* __restrict__ kT,
    const float2* __restrict__ tw, float2* __restrict__ spec)
{
    __shared__ float2 bufA[4096];
    __shared__ float2 bufB[4096];
    const int tid = threadIdx.x;
    const int bh = blockIdx.x >> 3, chunk = blockIdx.x & 7;
    float sx[16], sy[16];
#pragma unroll
    for (int i = 0; i < 16; i++) { sx[i] = 0.f; sy[i] = 0.f; }
    const _Float16* qb = qT + (size_t)bh * 64 * 4096;
    const _Float16* kb = kT + (size_t)bh * 64 * 4096;
    for (int dd = 0; dd < 8; dd++) {
        const int d = chunk * 8 + dd;
#pragma unroll
        for (int i = 0; i < 2; i++) {
            const int t0 = 2048 * i + tid * 8;
            const half8 fq = *(const half8*)(qb + d * 4096 + t0);
            const half8 fk = *(const half8*)(kb + d * 4096 + t0);
#pragma unroll
            for (int j = 0; j < 8; j++)
                bufA[swz(t0 + j)] = make_float2((float)fq[j], (float)fk[j]);
        }
        fft4096(bufA, bufB, tw, tid);
        // unpack packed transforms; accumulate S = Q * conj(K)
#pragma unroll
        for (int i = 0; i < 16; i++) {
            const int f = tid + 256 * i;
            const float2 Zf = bufA[swz(f)];
            const float2 Zm = bufA[swz((4096 - f) & 4095)];
            const float Qr  = 0.5f * (Zf.x + Zm.x);
            const float Qi  = 0.5f * (Zf.y - Zm.y);
            const float cKr = 0.5f * (Zf.y + Zm.y);
            const float cKi = 0.5f * (Zf.x - Zm.x);
            sx[i] += Qr * cKr - Qi * cKi;
            sy[i] += Qr * cKi + Qi * cKr;
        }
        __syncthreads();
    }
    float2* out = spec + (size_t)blockIdx.x * 4096;
#pragma unroll
    for (int i = 0; i < 16; i++) out[tid + 256 * i] = make_float2(sx[i], sy[i]);
}

// per block: one (b,h). Sum 8 partials, corr = Re(FFT(conj(S))); top-8 + softmax.
__global__ __launch_bounds__(256) void reduce_topk_kernel(
    const float2* __restrict__ spec, const float2* __restrict__ tw,
    int* __restrict__ top_idx, float* __restrict__ top_w)
{
    __shared__ float2 bufA[4096];
    __shared__ float2 bufB[4096];
    const int tid = threadIdx.x;
    const int bh = blockIdx.x;
#pragma unroll
    for (int i = 0; i < 16; i++) {
        const int f = tid + 256 * i;
        float sr = 0.f, si = 0.f;
        for (int c = 0; c < 8; c++) {
            const float2 v = spec[((size_t)(bh * 8 + c)) * 4096 + f];
            sr += v.x; si += v.y;
        }
        bufA[swz(f)] = make_float2(sr, -si);   // conj
    }
    fft4096(bufA, bufB, tw, tid);
    // bufA[tau].x ~ corr(tau) (unscaled). Top-8, lower-index tie-break.
    float* wv = (float*)bufB;        // bufB free after FFT
    int*   wi = (int*)bufB + 8;
    float vals[8]; int idxs[8];
    for (int k = 0; k < 8; k++) {
        float best = -3.0e38f; int bi = 0;
#pragma unroll
        for (int i = 0; i < 16; i++) {
            const int f = tid + 256 * i;
            const float c = bufA[swz(f)].x;
            if (c > best) { best = c; bi = f; }
        }
#pragma unroll
        for (int off = 32; off > 0; off >>= 1) {
            const float ov = __shfl_down(best, off);
            const int oi = __shfl_down(bi, off);
            if (ov > best || (ov == best && oi < bi)) { best = ov; bi = oi; }
        }
        if ((tid & 63) == 0) { wv[tid >> 6] = best; wi[tid >> 6] = bi; }
        __syncthreads();
        if (tid == 0) {
            best = wv[0]; bi = wi[0];
            for (int w = 1; w < 4; w++) {
                if (wv[w] > best || (wv[w] == best && wi[w] < bi)) { best = wv[w]; bi = wi[w]; }
            }
            vals[k] = best; idxs[k] = bi;
            bufA[swz(bi)].x = -3.4e38f;
        }
        __syncthreads();
    }
    if (tid == 0) {
        const float scale = 1.f / (4096.f * 64.f);
        float e[8], s = 0.f;
        const float mx = vals[0] * scale;
        for (int k = 0; k < 8; k++) { e[k] = __expf(vals[k] * scale - mx); s += e[k]; }
        for (int k = 0; k < 8; k++) {
            top_w[bh * 8 + k] = e[k] / s;
            top_idx[bh * 8 + k] = idxs[k];
        }
    }
}

// ---------- gather: out_pre[b,l,h*64+d] = sum_k w_k * v[b,h,(l+idx_k)%L,d] ----------
__global__ __launch_bounds__(256) void gather_kernel(
    const half2v* __restrict__ v2, const int* __restrict__ top_idx,
    const float* __restrict__ top_w, half2v* __restrict__ out2)
{
    const int seq = blockIdx.x;           // 32768
    const int bh = seq >> 9;
    const int lgrp = seq & 511;
    const int b = bh >> 3, h = bh & 7;
    const int tid = threadIdx.x;
    const int l = lgrp * 8 + (tid >> 5);
    const int d2 = tid & 31;              // half2 index
    int idx[8]; float w[8];
#pragma unroll
    for (int k = 0; k < 8; k++) { idx[k] = top_idx[bh * 8 + k]; w[k] = top_w[bh * 8 + k]; }
    const half2v* vb = v2 + (size_t)bh * 4096 * 32;
    float a0 = 0.f, a1 = 0.f;
#pragma unroll
    for (int k = 0; k < 8; k++) {
        const int ls = (l + idx[k]) & 4095;
        const half2v pv = vb[ls * 32 + d2];
        a0 += w[k] * (float)pv[0];
        a1 += w[k] * (float)pv[1];
    }
    half2v o; o[0] = (_Float16)a0; o[1] = (_Float16)a1;
    out2[((size_t)(b * 4096 + l)) * 256 + h * 32 + d2] = o;
}

// ---------- host ----------
extern "C" void kernel_launch(void* const* d_in, const int* in_sizes, int n_in,
                              void* d_out, int out_size, void* d_ws, size_t ws_size,
                              hipStream_t stream) {
    (void)in_sizes; (void)n_in; (void)out_size; (void)ws_size;
    const float* x  = (const float*)d_in[0];
    const float* Wq = (const float*)d_in[1];
    const float* bq = (const float*)d_in[2];
    const float* Wk = (const float*)d_in[3];
    const float* bk = (const float*)d_in[4];
    const float* Wv = (const float*)d_in[5];
    const float* bv = (const float*)d_in[6];
    const float* Wo = (const float*)d_in[7];
    const float* bo = (const float*)d_in[8];
    float* out = (float*)d_out;

    char* ws = (char*)d_ws;
    size_t off = 0;
    auto alloc = [&](size_t bytes) -> void* {
        void* p = ws + off; off += (bytes + 255) & ~(size_t)255; return p;
    };
    _Float16* xh   = (_Float16*)alloc(33554432);   // 32768x512 fp16
    _Float16* qT   = (_Float16*)alloc(33554432);   // (B,H,D,L) fp16
    _Float16* kT   = (_Float16*)alloc(33554432);
    _Float16* vbuf = (_Float16*)alloc(33554432);   // (B,H,L,D) fp16
    float2* spec   = (float2*)alloc(16777216);     // 512 x 4096 float2
    _Float16* BtH  = (_Float16*)alloc(1572864);    // 1536x512 fp16
    _Float16* WoH  = (_Float16*)alloc(524288);     // 512x512 fp16
    float* biasQKV = (float*)alloc(6144);          // 1536 fp32
    float2* tw     = (float2*)alloc(16384);        // 2048 twiddles
    int*   top_idx = (int*)alloc(2048);
    float* top_w   = (float*)alloc(2048);
    _Float16* out_pre = xh;                        // alias: xh dead after GEMM1

    prep_all_kernel<<<20494, 256, 0, stream>>>(x, Wq, Wk, Wv, Wo, bq, bk, bv,
                                               xh, BtH, WoH, tw, biasQKV);
    gemm_f16_kernel<0><<<3072, 256, 0, stream>>>(xh, BtH, biasQKV, qT, kT, vbuf, nullptr);
    fft_partial_kernel<<<512, 256, 0, stream>>>(qT, kT, tw, spec);
    reduce_topk_kernel<<<64, 256, 0, stream>>>(spec, tw, top_idx, top_w);
    gather_kernel<<<32768, 256, 0, stream>>>((const half2v*)vbuf, top_idx, top_w,
                                             (half2v*)out_pre);
    gemm_f16_kernel<1><<<1024, 256, 0, stream>>>(out_pre, WoH, bo, nullptr, nullptr, nullptr, out);
}